// Round 7
// baseline (276.585 us; speedup 1.0000x reference)
//
#include <hip/hip_runtime.h>
#include <hip/hip_cooperative_groups.h>

namespace cg = cooperative_groups;

#define NN 2048
#define DD 64
#define C1 0.36067376f  // 2/sqrt(D) * log2(e)
#define C1H 0.18033688f // C1/2

typedef _Float16 h8 __attribute__((ext_vector_type(8)));
typedef _Float16 h4 __attribute__((ext_vector_type(4)));
typedef float fx4 __attribute__((ext_vector_type(4)));
typedef float f32x16 __attribute__((ext_vector_type(16)));

// raw asm global loads: invisible to compiler's waitcnt pass -> it can
// neither sink them to first use nor drain them with vmcnt(0)
#define GL4(dst, ap, off) \
    asm volatile("global_load_dwordx4 %0, %1, off offset:" off \
                 : "=v"(dst) : "v"(ap))

// stage-wait: ties all 12 stage regs, so consumers can't hoist above it and
// the producing loads can't sink below it
#define WAITS(cnt, K, V, H) \
    asm volatile("s_waitcnt vmcnt(" cnt ")" \
        : "+v"(K[0]), "+v"(K[1]), "+v"(K[2]), "+v"(K[3]), \
          "+v"(V[0]), "+v"(V[1]), "+v"(V[2]), "+v"(V[3]), \
          "+v"(H[0]), "+v"(H[1]), "+v"(H[2]), "+v"(H[3]))

// ---- phase 1: prep 64 K/V rows of one bh into frag-major Ks/Vs + hk ----
__device__ __forceinline__ void prep_phase(
    int bh, int s, int tid,
    const float* __restrict__ k, const float* __restrict__ v,
    _Float16* __restrict__ Ks, _Float16* __restrict__ Vs,
    float* __restrict__ hkw, _Float16 (*T)[72])
{
    const size_t ibase = (size_t)bh * NN * DD + (size_t)s * 64 * DD;
    // K: coalesced load + f16 LDS + row sumsq
#pragma unroll
    for (int it = 0; it < 8; ++it) {
        int f = tid + 128 * it;          // 1024 float4 = 64 rows x 16
        int row = f >> 4, c4 = (f & 15) * 4;
        float4 a = *(const float4*)&k[ibase + (size_t)row * DD + c4];
        h4 hv = {(_Float16)a.x, (_Float16)a.y, (_Float16)a.z, (_Float16)a.w};
        *(h4*)&T[row][c4] = hv;
        float sq = a.x * a.x + a.y * a.y + a.z * a.z + a.w * a.w;
        sq += __shfl_xor(sq, 1, 16);
        sq += __shfl_xor(sq, 2, 16);
        sq += __shfl_xor(sq, 4, 16);
        sq += __shfl_xor(sq, 8, 16);
        if ((tid & 15) == 0) hkw[bh * NN + s * 64 + row] = sq * C1H;
    }
    __syncthreads();
#pragma unroll
    for (int it = 0; it < 4; ++it) {     // 512 h8 recs: 2 tiles x 4c x 64 lanes
        int rec = tid + 128 * it;
        int tl = rec >> 8, c = (rec >> 6) & 3, lr = rec & 63;
        int lnr = lr & 31, lhr = lr >> 5;
        h8 r = *(const h8*)&T[32 * tl + lnr][16 * c + 8 * lhr];
        *(h8*)&Ks[(size_t)bh * 131072 + (size_t)(s * 2 + tl) * 2048
                  + (size_t)(c * 64 + lr) * 8] = r;
    }
    __syncthreads();
    // V: coalesced load + f16 LDS + transposed frag gather
#pragma unroll
    for (int it = 0; it < 8; ++it) {
        int f = tid + 128 * it;
        int row = f >> 4, c4 = (f & 15) * 4;
        float4 a = *(const float4*)&v[ibase + (size_t)row * DD + c4];
        h4 hv = {(_Float16)a.x, (_Float16)a.y, (_Float16)a.z, (_Float16)a.w};
        *(h4*)&T[row][c4] = hv;
    }
    __syncthreads();
#pragma unroll
    for (int it = 0; it < 4; ++it) {     // 512 recs: 2 tiles x 2o x 2c x 64 lanes
        int rec = tid + 128 * it;
        int tl = rec >> 8, o = (rec >> 7) & 1, c = (rec >> 6) & 1, lr = rec & 63;
        int lnr = lr & 31, lhr = lr >> 5;
        h8 r;
#pragma unroll
        for (int jx = 0; jx < 8; ++jx)
            r[jx] = T[32 * tl + 16 * c + 8 * lhr + jx][32 * o + lnr];
        *(h8*)&Vs[(size_t)bh * 131072 + (size_t)(s * 2 + tl) * 2048
                  + (size_t)(o * 128 + c * 64 + lr) * 8] = r;
    }
}

// ---- phase 2: flash RBF, hand-pipelined asm loads + explicit vmcnt ----
__device__ __forceinline__ void attn_phase(
    int bh, int qb, int tid,
    const float* __restrict__ q, const _Float16* __restrict__ Ks,
    const _Float16* __restrict__ Vs, const float* __restrict__ hkw,
    float* __restrict__ out)
{
    const int wv = tid >> 6, lane = tid & 63;
    const int ln = lane & 31, lh = lane >> 5;
    const int jmax = 2 * qb + wv;
    const int qrow = qb * 64 + wv * 32 + ln;
    const size_t fbase = (size_t)bh * NN * DD;

    h8 qf[4];
    {
        const float* qr = q + fbase + (size_t)qrow * DD;
#pragma unroll
        for (int c = 0; c < 4; ++c) {
            float4 a = *(const float4*)&qr[16 * c + 8 * lh];
            float4 b = *(const float4*)&qr[16 * c + 8 * lh + 4];
            qf[c] = h8{(_Float16)a.x, (_Float16)a.y, (_Float16)a.z, (_Float16)a.w,
                       (_Float16)b.x, (_Float16)b.y, (_Float16)b.z, (_Float16)b.w};
        }
    }

    const unsigned long long kb0 =
        (unsigned long long)Ks + (size_t)bh * 262144 + (size_t)lane * 16;
    const unsigned long long vb0 =
        (unsigned long long)Vs + (size_t)bh * 262144 + (size_t)lane * 16;
    const unsigned long long hb0 =
        (unsigned long long)(hkw + bh * NN) + (size_t)lh * 16;

    f32x16 O0, O1;
#pragma unroll
    for (int r = 0; r < 16; ++r) { O0[r] = 0.f; O1[r] = 0.f; }
    float lsum = 0.f, mrun = -INFINITY;

#define ISSUE(jjv, K, V, H) do { \
        unsigned long long kp = kb0 + (unsigned long long)(jjv) * 4096; \
        unsigned long long vp = vb0 + (unsigned long long)(jjv) * 4096; \
        unsigned long long hp = hb0 + (unsigned long long)(jjv) * 128;  \
        GL4(K[0], kp, "0"); GL4(K[1], kp, "1024"); \
        GL4(K[2], kp, "2048"); GL4(K[3], kp, "3072"); \
        GL4(V[0], vp, "0"); GL4(V[1], vp, "1024"); \
        GL4(V[2], vp, "2048"); GL4(V[3], vp, "3072"); \
        GL4(H[0], hp, "0"); GL4(H[1], hp, "32"); \
        GL4(H[2], hp, "64"); GL4(H[3], hp, "96"); \
    } while (0)

    auto comp = [&](int jj, fx4 (&K)[4], fx4 (&V)[4], fx4 (&H)[4]) {
        f32x16 S;
#pragma unroll
        for (int r = 0; r < 16; ++r) S[r] = 0.f;
#pragma unroll
        for (int c = 0; c < 4; ++c) {
            h8 kf; __builtin_memcpy(&kf, &K[c], 16);
            S = __builtin_amdgcn_mfma_f32_32x32x16_f16(kf, qf[c], S, 0, 0, 0);
        }
        const bool diag = (jj == jmax);
#pragma unroll
        for (int r = 0; r < 16; ++r) {
            float hv = ((const float*)&H[r >> 2])[r & 3];
            float xv = fmaf(S[r], C1, -hv);
            if (diag && ((r & 3) + 8 * (r >> 2) + 4 * lh > ln)) xv = -INFINITY;
            S[r] = xv;
        }
        float mt = S[0];
#pragma unroll
        for (int r = 1; r < 16; ++r) mt = fmaxf(mt, S[r]);
        mt = fmaxf(mt, __shfl_xor(mt, 32));
        if (__ballot(mt > mrun) != 0ull) {   // max rarely rises after early tiles
            float mnew = fmaxf(mrun, mt);
            float alpha = __builtin_amdgcn_exp2f(mrun - mnew);
            mrun = mnew;
            lsum *= alpha;
#pragma unroll
            for (int r = 0; r < 16; ++r) { O0[r] *= alpha; O1[r] *= alpha; }
        }
        unsigned pk[8];
        float ps = 0.f;
#pragma unroll
        for (int hh = 0; hh < 8; ++hh) {
            float p0 = __builtin_amdgcn_exp2f(S[2 * hh] - mrun);
            float p1 = __builtin_amdgcn_exp2f(S[2 * hh + 1] - mrun);
            ps += p0 + p1;
            auto pr = __builtin_amdgcn_cvt_pkrtz(p0, p1);
            unsigned pu; __builtin_memcpy(&pu, &pr, 4);
            pk[hh] = pu;
        }
        lsum += ps;
#pragma unroll
        for (int s = 0; s < 2; ++s) {        // C-frag -> B-frag(P^T): lane^32 swap
            unsigned send0 = lh ? pk[4 * s + 0] : pk[4 * s + 2];
            unsigned send1 = lh ? pk[4 * s + 1] : pk[4 * s + 3];
            unsigned r0 = (unsigned)__shfl_xor((int)send0, 32);
            unsigned r1 = (unsigned)__shfl_xor((int)send1, 32);
            unsigned pb[4];
            pb[0] = lh ? r0 : pk[4 * s + 0];
            pb[1] = lh ? r1 : pk[4 * s + 1];
            pb[2] = lh ? pk[4 * s + 2] : r0;
            pb[3] = lh ? pk[4 * s + 3] : r1;
            h8 pbv; __builtin_memcpy(&pbv, pb, 16);
            h8 v0; __builtin_memcpy(&v0, &V[s], 16);
            h8 v1; __builtin_memcpy(&v1, &V[2 + s], 16);
            O0 = __builtin_amdgcn_mfma_f32_32x32x16_f16(v0, pbv, O0, 0, 0, 0);
            O1 = __builtin_amdgcn_mfma_f32_32x32x16_f16(v1, pbv, O1, 0, 0, 0);
        }
    };

    fx4 KA[4], VA[4], HA[4], KB[4], VB[4], HB[4];
    ISSUE(0, KA, VA, HA);
    int jj = 0;
    while (true) {
        if (jj < jmax) { ISSUE(jj + 1, KB, VB, HB); WAITS("12", KA, VA, HA); }
        else           { WAITS("0", KA, VA, HA); }
        comp(jj, KA, VA, HA);
        if (++jj > jmax) break;
        if (jj < jmax) { ISSUE(jj + 1, KA, VA, HA); WAITS("12", KB, VB, HB); }
        else           { WAITS("0", KB, VB, HB); }
        comp(jj, KB, VB, HB);
        if (++jj > jmax) break;
    }
#undef ISSUE

    float lt = lsum + __shfl_xor(lsum, 32);
    float inv = 1.f / lt;
    size_t ro = fbase + (size_t)qrow * DD;
#pragma unroll
    for (int g = 0; g < 4; ++g) {
        float4 o0 = make_float4(O0[4 * g + 0] * inv, O0[4 * g + 1] * inv,
                                O0[4 * g + 2] * inv, O0[4 * g + 3] * inv);
        *(float4*)&out[ro + 8 * g + 4 * lh] = o0;
        float4 o1 = make_float4(O1[4 * g + 0] * inv, O1[4 * g + 1] * inv,
                                O1[4 * g + 2] * inv, O1[4 * g + 3] * inv);
        *(float4*)&out[ro + 32 + 8 * g + 4 * lh] = o1;
    }
}

// ---- fused cooperative kernel: prep -> grid sync -> attention ----
__global__ __launch_bounds__(128, 2) void fused(
    const float* __restrict__ q, const float* __restrict__ k,
    const float* __restrict__ v, float* __restrict__ hkw,
    _Float16* __restrict__ Ks, _Float16* __restrict__ Vs,
    float* __restrict__ out)
{
    __shared__ _Float16 T[64][72];
    prep_phase(blockIdx.x, blockIdx.y, threadIdx.x, k, v, Ks, Vs, hkw, T);
    cg::this_grid().sync();
    attn_phase(blockIdx.x, 31 - blockIdx.y, threadIdx.x, q, Ks, Vs, hkw, out);
}

// ---- fallback pair (if cooperative enqueue is rejected under capture) ----
__global__ __launch_bounds__(128) void prep_k(
    const float* __restrict__ k, const float* __restrict__ v,
    float* __restrict__ hkw, _Float16* __restrict__ Ks,
    _Float16* __restrict__ Vs)
{
    __shared__ _Float16 T[64][72];
    prep_phase(blockIdx.x, blockIdx.y, threadIdx.x, k, v, Ks, Vs, hkw, T);
}

__global__ __launch_bounds__(128, 2) void attn_k(
    const float* __restrict__ q, const _Float16* __restrict__ Ks,
    const _Float16* __restrict__ Vs, const float* __restrict__ hkw,
    float* __restrict__ out)
{
    attn_phase(blockIdx.x, 31 - blockIdx.y, threadIdx.x, q, Ks, Vs, hkw, out);
}

extern "C" void kernel_launch(void* const* d_in, const int* in_sizes, int n_in,
                              void* d_out, int out_size, void* d_ws, size_t ws_size,
                              hipStream_t stream) {
    (void)in_sizes; (void)n_in; (void)out_size; (void)ws_size;
    const float* q = (const float*)d_in[0];
    const float* k = (const float*)d_in[1];
    const float* v = (const float*)d_in[2];
    float* out = (float*)d_out;

    // ws: [hk 256KB][Ks 8MB f16][Vs 8MB f16]
    float* hkw = (float*)d_ws;
    _Float16* Ks = (_Float16*)((char*)d_ws + 262144);
    _Float16* Vs = (_Float16*)((char*)d_ws + 262144 + 8388608);

    void* args[7] = {(void*)&q, (void*)&k, (void*)&v, (void*)&hkw,
                     (void*)&Ks, (void*)&Vs, (void*)&out};
    hipError_t e = hipLaunchCooperativeKernel((const void*)fused, dim3(32, 32),
                                              dim3(128, 1, 1), args, 0, stream);
    if (e != hipSuccess) {
        prep_k<<<dim3(32, 32), 128, 0, stream>>>(k, v, hkw, Ks, Vs);
        attn_k<<<dim3(32, 32), 128, 0, stream>>>(q, Ks, Vs, hkw, out);
    }
}